// Round 5
// baseline (320.826 us; speedup 1.0000x reference)
//
#include <hip/hip_runtime.h>

// HierarchicalClassifier: B=16384, D=2048, N_TOP=8, N_CLASS=16
// out[b, t*16+c] = sigmoid(f.top_W[t]+top_b[t]) * softmax_c(f.bottom_W[t,:,c]+bottom_b[t,c])
//
// R5 = R4 with the cvt_pkrtz type fix (builtin returns __fp16x2, not _Float16x2).
// Manual register double-buffer in the K-loop: R2 showed VGPR=60 -> compiler
// serialized all 13 loads/step behind per-load waitcnts (93% stall). Named
// prefetch buffers force ~13 loads in flight with fine-grained vmcnt.

#define D_DIM 2048
#define NTILE 9          // 144 columns / 16
#define M_ROWS 32        // rows per workgroup (2 row-tiles of 16)

using f32x4 = float __attribute__((ext_vector_type(4)));
using half8 = _Float16 __attribute__((ext_vector_type(8)));
using fp16x2 = __fp16 __attribute__((ext_vector_type(2)));

// Swizzled B layout: S[(((w*16 + ks)*9 + nt)*64 + lane)*8 + j]
//   = W[n = nt*16 + (lane&15)][k = w*512 + ks*32 + (lane>>4)*8 + j]
// W rows 0..7 = top_W, 8..135 = bottom_W[t][:,c] (n-8 = t*16+c), 136..143 = 0.
__global__ void prep_weights(const float* __restrict__ topW,
                             const float* __restrict__ botW,
                             _Float16* __restrict__ S) {
    int idx = blockIdx.x * blockDim.x + threadIdx.x;   // [0, 4*16*9*64)
    if (idx >= 4 * 16 * NTILE * 64) return;
    int lane = idx & 63;
    int tmp  = idx >> 6;          // (w*16+ks)*9 + nt
    int nt   = tmp % NTILE;
    int wks  = tmp / NTILE;       // w*16+ks in [0,64)
    int n     = nt * 16 + (lane & 15);
    int kbase = wks * 32 + (lane >> 4) * 8;

    _Float16 v[8];
    #pragma unroll
    for (int j = 0; j < 8; j++) {
        int k = kbase + j;
        float x = 0.0f;
        if (n < 8) {
            x = topW[n * D_DIM + k];
        } else if (n < 136) {
            int t = (n - 8) >> 4, c = (n - 8) & 15;
            x = botW[(t * D_DIM + k) * 16 + c];
        }
        v[j] = (_Float16)x;
    }
    *(half8*)(S + (size_t)idx * 8) = *(half8*)v;
}

static __device__ __forceinline__ half8 pack_af(f32x4 a, f32x4 b) {
    fp16x2 p0 = __builtin_amdgcn_cvt_pkrtz(a[0], a[1]);
    fp16x2 p1 = __builtin_amdgcn_cvt_pkrtz(a[2], a[3]);
    fp16x2 p2 = __builtin_amdgcn_cvt_pkrtz(b[0], b[1]);
    fp16x2 p3 = __builtin_amdgcn_cvt_pkrtz(b[2], b[3]);
    half8 r;
    r[0] = (_Float16)p0[0]; r[1] = (_Float16)p0[1];
    r[2] = (_Float16)p1[0]; r[3] = (_Float16)p1[1];
    r[4] = (_Float16)p2[0]; r[5] = (_Float16)p2[1];
    r[6] = (_Float16)p3[0]; r[7] = (_Float16)p3[1];
    return r;
}

__global__ __launch_bounds__(256, 2) void hc_fused(
        const float* __restrict__ feat, const _Float16* __restrict__ Bsw,
        const float* __restrict__ top_b, const float* __restrict__ bot_b,
        float* __restrict__ out) {
    __shared__ float red[4][M_ROWS][148];   // [wave][row][ncol(+pad)] = 74 KB

    const int tid  = threadIdx.x;
    const int lane = tid & 63, wave = tid >> 6;
    const int quad = lane >> 4, low = lane & 15;
    const size_t row0 = (size_t)blockIdx.x * M_ROWS;

    // A: lane holds A[m=low][k = quad*8 + j]; this wave's K range = [wave*512, +512)
    const float* A0 = feat + (row0 + low) * D_DIM + wave * 512 + quad * 8;
    const float* A1 = A0 + 16 * D_DIM;
    // B: swizzled fragment stream; per (ks,nt) a contiguous 1KB wave read.
    const _Float16* Bp = Bsw + (size_t)wave * (16 * NTILE * 512) + lane * 8;

    f32x4 acc0[NTILE], acc1[NTILE];
    #pragma unroll
    for (int i = 0; i < NTILE; i++) { acc0[i] = (f32x4)0.0f; acc1[i] = (f32x4)0.0f; }

    // --- software pipeline: register double-buffer, depth 1 ---
    half8 bB[2][NTILE];
    f32x4 bA[2][4];

    #pragma unroll
    for (int nt = 0; nt < NTILE; nt++) bB[0][nt] = *(const half8*)(Bp + nt * 512);
    bA[0][0] = *(const f32x4*)(A0);
    bA[0][1] = *(const f32x4*)(A0 + 4);
    bA[0][2] = *(const f32x4*)(A1);
    bA[0][3] = *(const f32x4*)(A1 + 4);

    #pragma unroll 2
    for (int ks = 0; ks < 16; ks++) {
        const int cur = ks & 1, nxt = cur ^ 1;
        if (ks < 15) {
            const _Float16* Bn = Bp + (size_t)(ks + 1) * NTILE * 512;
            #pragma unroll
            for (int nt = 0; nt < NTILE; nt++)
                bB[nxt][nt] = *(const half8*)(Bn + nt * 512);
            const float* a0 = A0 + (ks + 1) * 32;
            const float* a1 = A1 + (ks + 1) * 32;
            bA[nxt][0] = *(const f32x4*)(a0);
            bA[nxt][1] = *(const f32x4*)(a0 + 4);
            bA[nxt][2] = *(const f32x4*)(a1);
            bA[nxt][3] = *(const f32x4*)(a1 + 4);
        }
        const half8 af0 = pack_af(bA[cur][0], bA[cur][1]);
        const half8 af1 = pack_af(bA[cur][2], bA[cur][3]);
        #pragma unroll
        for (int nt = 0; nt < NTILE; nt++) {
            acc0[nt] = __builtin_amdgcn_mfma_f32_16x16x32_f16(af0, bB[cur][nt], acc0[nt], 0, 0, 0);
            acc1[nt] = __builtin_amdgcn_mfma_f32_16x16x32_f16(af1, bB[cur][nt], acc1[nt], 0, 0, 0);
        }
    }

    // C/D layout (measured m89/m91): col = lane&15, row = quad*4 + reg.
    #pragma unroll
    for (int nt = 0; nt < NTILE; nt++) {
        #pragma unroll
        for (int r = 0; r < 4; r++) {
            red[wave][quad * 4 + r][nt * 16 + low]      = acc0[nt][r];
            red[wave][16 + quad * 4 + r][nt * 16 + low] = acc1[nt][r];
        }
    }
    __syncthreads();

    // Epilogue: thread -> (row = tid>>3 in [0,32), top = tid&7). All active.
    const int row = tid >> 3;
    const int top = tid & 7;
    {
        float zt = top_b[top];
        #pragma unroll
        for (int w = 0; w < 4; w++) zt += red[w][row][top];
        const float sig = 1.0f / (1.0f + __expf(-zt));

        float z[16];
        float zmax = -1e30f;
        #pragma unroll
        for (int c = 0; c < 16; c++) {
            float v = bot_b[top * 16 + c];
            #pragma unroll
            for (int w = 0; w < 4; w++) v += red[w][row][8 + top * 16 + c];
            z[c] = v;
            zmax = fmaxf(zmax, v);
        }
        float s = 0.0f;
        #pragma unroll
        for (int c = 0; c < 16; c++) { z[c] = __expf(z[c] - zmax); s += z[c]; }
        const float scale = sig / s;

        float* o = out + (row0 + row) * 128 + top * 16;
        #pragma unroll
        for (int c = 0; c < 16; c += 4) {
            f32x4 v = { z[c] * scale, z[c+1] * scale, z[c+2] * scale, z[c+3] * scale };
            *(f32x4*)(o + c) = v;
        }
    }
}

extern "C" void kernel_launch(void* const* d_in, const int* in_sizes, int n_in,
                              void* d_out, int out_size, void* d_ws, size_t ws_size,
                              hipStream_t stream) {
    const float* feat  = (const float*)d_in[0];   // (16384, 2048)
    const float* topW  = (const float*)d_in[1];   // (8, 2048)
    const float* topB  = (const float*)d_in[2];   // (8,)
    const float* botW  = (const float*)d_in[3];   // (8, 2048, 16)
    const float* botB  = (const float*)d_in[4];   // (8, 16)
    float* out = (float*)d_out;                   // (16384, 128)
    _Float16* Bsw = (_Float16*)d_ws;              // 144*2048 fp16 = 576 KB swizzled

    prep_weights<<<(4 * 16 * NTILE * 64 + 255) / 256, 256, 0, stream>>>(topW, botW, Bsw);
    hc_fused<<<16384 / M_ROWS, 256, 0, stream>>>(feat, Bsw, topB, botB, out);
}

// Round 6
// 205.557 us; speedup vs baseline: 1.5608x; 1.5608x over previous
//
#include <hip/hip_runtime.h>

// HierarchicalClassifier: B=16384, D=2048, N_TOP=8, N_CLASS=16
// out[b, t*16+c] = sigmoid(f.top_W[t]+top_b[t]) * softmax_c(f.bottom_W[t,:,c]+bottom_b[t,c])
//
// R6: register double-buffer done SROA-safely. R5's bB[2][9]/bA[2][4] indexed
// by (ks&1) defeated SROA -> arrays in scratch -> 303 MB scratch writes, 174us.
// Fix: two separate named buffer sets + source-level 2x-unrolled K loop, so
// all indexing is constant-trip (the pattern that promoted fine in R2/R3).

#define D_DIM 2048
#define NTILE 9          // 144 columns / 16
#define M_ROWS 32        // rows per workgroup (2 row-tiles of 16)

using f32x4 = float __attribute__((ext_vector_type(4)));
using half8 = _Float16 __attribute__((ext_vector_type(8)));
using fp16x2 = __fp16 __attribute__((ext_vector_type(2)));

// Swizzled B layout: S[(((w*16 + ks)*9 + nt)*64 + lane)*8 + j]
//   = W[n = nt*16 + (lane&15)][k = w*512 + ks*32 + (lane>>4)*8 + j]
// W rows 0..7 = top_W, 8..135 = bottom_W[t][:,c] (n-8 = t*16+c), 136..143 = 0.
__global__ void prep_weights(const float* __restrict__ topW,
                             const float* __restrict__ botW,
                             _Float16* __restrict__ S) {
    int idx = blockIdx.x * blockDim.x + threadIdx.x;   // [0, 4*16*9*64)
    if (idx >= 4 * 16 * NTILE * 64) return;
    int lane = idx & 63;
    int tmp  = idx >> 6;          // (w*16+ks)*9 + nt
    int nt   = tmp % NTILE;
    int wks  = tmp / NTILE;       // w*16+ks in [0,64)
    int n     = nt * 16 + (lane & 15);
    int kbase = wks * 32 + (lane >> 4) * 8;

    _Float16 v[8];
    #pragma unroll
    for (int j = 0; j < 8; j++) {
        int k = kbase + j;
        float x = 0.0f;
        if (n < 8) {
            x = topW[n * D_DIM + k];
        } else if (n < 136) {
            int t = (n - 8) >> 4, c = (n - 8) & 15;
            x = botW[(t * D_DIM + k) * 16 + c];
        }
        v[j] = (_Float16)x;
    }
    *(half8*)(S + (size_t)idx * 8) = *(half8*)v;
}

static __device__ __forceinline__ half8 pack_af(f32x4 a, f32x4 b) {
    fp16x2 p0 = __builtin_amdgcn_cvt_pkrtz(a[0], a[1]);
    fp16x2 p1 = __builtin_amdgcn_cvt_pkrtz(a[2], a[3]);
    fp16x2 p2 = __builtin_amdgcn_cvt_pkrtz(b[0], b[1]);
    fp16x2 p3 = __builtin_amdgcn_cvt_pkrtz(b[2], b[3]);
    half8 r;
    r[0] = (_Float16)p0[0]; r[1] = (_Float16)p0[1];
    r[2] = (_Float16)p1[0]; r[3] = (_Float16)p1[1];
    r[4] = (_Float16)p2[0]; r[5] = (_Float16)p2[1];
    r[6] = (_Float16)p3[0]; r[7] = (_Float16)p3[1];
    return r;
}

__global__ __launch_bounds__(256, 2) void hc_fused(
        const float* __restrict__ feat, const _Float16* __restrict__ Bsw,
        const float* __restrict__ top_b, const float* __restrict__ bot_b,
        float* __restrict__ out) {
    __shared__ float red[4][M_ROWS][148];   // [wave][row][ncol(+pad)] = 74 KB

    const int tid  = threadIdx.x;
    const int lane = tid & 63, wave = tid >> 6;
    const int quad = lane >> 4, low = lane & 15;
    const size_t row0 = (size_t)blockIdx.x * M_ROWS;

    // A: lane holds A[m=low][k = quad*8 + j]; this wave's K range = [wave*512, +512)
    const float* A0 = feat + (row0 + low) * D_DIM + wave * 512 + quad * 8;
    const float* A1 = A0 + 16 * D_DIM;
    // B: swizzled fragment stream; per (ks,nt) a contiguous 1KB wave read.
    const _Float16* Bp = Bsw + (size_t)wave * (16 * NTILE * 512) + lane * 8;

    f32x4 acc0[NTILE], acc1[NTILE];
    #pragma unroll
    for (int i = 0; i < NTILE; i++) { acc0[i] = (f32x4)0.0f; acc1[i] = (f32x4)0.0f; }

    // --- software pipeline: two named register buffer sets (SROA-safe) ---
    half8 bB0[NTILE], bB1[NTILE];
    f32x4 bA0[4], bA1[4];

    #pragma unroll
    for (int nt = 0; nt < NTILE; nt++) bB0[nt] = *(const half8*)(Bp + nt * 512);
    bA0[0] = *(const f32x4*)(A0);
    bA0[1] = *(const f32x4*)(A0 + 4);
    bA0[2] = *(const f32x4*)(A1);
    bA0[3] = *(const f32x4*)(A1 + 4);

    for (int ks = 0; ks < 16; ks += 2) {
        // prefetch odd step (ks+1) into set 1  (ks+1 <= 15 always)
        {
            const _Float16* Bn = Bp + (size_t)(ks + 1) * NTILE * 512;
            #pragma unroll
            for (int nt = 0; nt < NTILE; nt++)
                bB1[nt] = *(const half8*)(Bn + nt * 512);
            const float* a0 = A0 + (ks + 1) * 32;
            const float* a1 = A1 + (ks + 1) * 32;
            bA1[0] = *(const f32x4*)(a0);
            bA1[1] = *(const f32x4*)(a0 + 4);
            bA1[2] = *(const f32x4*)(a1);
            bA1[3] = *(const f32x4*)(a1 + 4);
        }
        // compute even step from set 0
        {
            const half8 af0 = pack_af(bA0[0], bA0[1]);
            const half8 af1 = pack_af(bA0[2], bA0[3]);
            #pragma unroll
            for (int nt = 0; nt < NTILE; nt++) {
                acc0[nt] = __builtin_amdgcn_mfma_f32_16x16x32_f16(af0, bB0[nt], acc0[nt], 0, 0, 0);
                acc1[nt] = __builtin_amdgcn_mfma_f32_16x16x32_f16(af1, bB0[nt], acc1[nt], 0, 0, 0);
            }
        }
        // prefetch next even step (ks+2) into set 0
        if (ks < 14) {
            const _Float16* Bn = Bp + (size_t)(ks + 2) * NTILE * 512;
            #pragma unroll
            for (int nt = 0; nt < NTILE; nt++)
                bB0[nt] = *(const half8*)(Bn + nt * 512);
            const float* a0 = A0 + (ks + 2) * 32;
            const float* a1 = A1 + (ks + 2) * 32;
            bA0[0] = *(const f32x4*)(a0);
            bA0[1] = *(const f32x4*)(a0 + 4);
            bA0[2] = *(const f32x4*)(a1);
            bA0[3] = *(const f32x4*)(a1 + 4);
        }
        // compute odd step from set 1
        {
            const half8 af0 = pack_af(bA1[0], bA1[1]);
            const half8 af1 = pack_af(bA1[2], bA1[3]);
            #pragma unroll
            for (int nt = 0; nt < NTILE; nt++) {
                acc0[nt] = __builtin_amdgcn_mfma_f32_16x16x32_f16(af0, bB1[nt], acc0[nt], 0, 0, 0);
                acc1[nt] = __builtin_amdgcn_mfma_f32_16x16x32_f16(af1, bB1[nt], acc1[nt], 0, 0, 0);
            }
        }
    }

    // C/D layout (measured m89/m91): col = lane&15, row = quad*4 + reg.
    #pragma unroll
    for (int nt = 0; nt < NTILE; nt++) {
        #pragma unroll
        for (int r = 0; r < 4; r++) {
            red[wave][quad * 4 + r][nt * 16 + low]      = acc0[nt][r];
            red[wave][16 + quad * 4 + r][nt * 16 + low] = acc1[nt][r];
        }
    }
    __syncthreads();

    // Epilogue: thread -> (row = tid>>3 in [0,32), top = tid&7). All active.
    const int row = tid >> 3;
    const int top = tid & 7;
    {
        float zt = top_b[top];
        #pragma unroll
        for (int w = 0; w < 4; w++) zt += red[w][row][top];
        const float sig = 1.0f / (1.0f + __expf(-zt));

        float z[16];
        float zmax = -1e30f;
        #pragma unroll
        for (int c = 0; c < 16; c++) {
            float v = bot_b[top * 16 + c];
            #pragma unroll
            for (int w = 0; w < 4; w++) v += red[w][row][8 + top * 16 + c];
            z[c] = v;
            zmax = fmaxf(zmax, v);
        }
        float s = 0.0f;
        #pragma unroll
        for (int c = 0; c < 16; c++) { z[c] = __expf(z[c] - zmax); s += z[c]; }
        const float scale = sig / s;

        float* o = out + (row0 + row) * 128 + top * 16;
        #pragma unroll
        for (int c = 0; c < 16; c += 4) {
            f32x4 v = { z[c] * scale, z[c+1] * scale, z[c+2] * scale, z[c+3] * scale };
            *(f32x4*)(o + c) = v;
        }
    }
}

extern "C" void kernel_launch(void* const* d_in, const int* in_sizes, int n_in,
                              void* d_out, int out_size, void* d_ws, size_t ws_size,
                              hipStream_t stream) {
    const float* feat  = (const float*)d_in[0];   // (16384, 2048)
    const float* topW  = (const float*)d_in[1];   // (8, 2048)
    const float* topB  = (const float*)d_in[2];   // (8,)
    const float* botW  = (const float*)d_in[3];   // (8, 2048, 16)
    const float* botB  = (const float*)d_in[4];   // (8, 16)
    float* out = (float*)d_out;                   // (16384, 128)
    _Float16* Bsw = (_Float16*)d_ws;              // 144*2048 fp16 = 576 KB swizzled

    prep_weights<<<(4 * 16 * NTILE * 64 + 255) / 256, 256, 0, stream>>>(topW, botW, Bsw);
    hc_fused<<<16384 / M_ROWS, 256, 0, stream>>>(feat, Bsw, topB, botB, out);
}